// Round 8
// baseline (219.861 us; speedup 1.0000x reference)
//
#include <hip/hip_runtime.h>
#include <math.h>

typedef short short8v __attribute__((ext_vector_type(8)));
typedef float float4v __attribute__((ext_vector_type(4)));

#define N_PTS 8192
#define HDIM  512
#define NHID  5
#define KSTR  1024   // shorts per weight row: 16 kb x (32 hi + 32 lo)
#define NCH   16     // conv j-chunks of 512

// byte offsets in workspace
#define OFF_WT    33554432ull
#define OFF_Y     38797312ull
#define OFF_DPSI  38961152ull
#define OFF_WSW   39124992ull
#define OFF_PART  39157760ull
#define OFF_BPART 41779200ull

__device__ __forceinline__ unsigned short f2bf(float x) {
  unsigned u = __builtin_bit_cast(unsigned, x);
  u += 0x7FFFu + ((u >> 16) & 1u);
  return (unsigned short)(u >> 16);
}
__device__ __forceinline__ float bf2f(unsigned short h) {
  unsigned u = ((unsigned)h) << 16;
  return __builtin_bit_cast(float, u);
}

// ---------------- W prep: transpose + split, interleaved hi|lo layout -------
// Wh [5][512(k)][512(n)] f32 -> WT [5][512(n)][16 kb][32 hi | 32 lo] bf16
__global__ void wprep_kernel(const float* __restrict__ Wh,
                             unsigned short* __restrict__ WT) {
  __shared__ float tile[32][33];
  int l = blockIdx.z;
  int kb = blockIdx.x;                 // k-tile of 32
  int n0 = blockIdx.y * 32;
  int j = threadIdx.x & 31, i8 = threadIdx.x >> 5;
  const float* W = Wh + (size_t)l * HDIM * HDIM;
#pragma unroll
  for (int q = 0; q < 4; ++q)
    tile[i8 + 8 * q][j] = W[(size_t)(kb * 32 + i8 + 8 * q) * HDIM + n0 + j];
  __syncthreads();
#pragma unroll
  for (int q = 0; q < 4; ++q) {
    int n = n0 + i8 + 8 * q;           // output row (col of W)
    float v = tile[j][i8 + 8 * q];     // W[kb*32+j][n]
    unsigned short h = f2bf(v);
    unsigned short lo = f2bf(v - bf2f(h));
    size_t o = ((size_t)l * HDIM + n) * KSTR + kb * 64 + j;
    WT[o] = h; WT[o + 32] = lo;
  }
}

// ---------------- fused MLP: input layer + 5 hidden GEMMs + out/softmax -----
// 256 blocks (1/CU) x 512 thr (8 waves). Block owns 32 rows; activation panel
// 32x512 lives in LDS (split bf16 hi|lo, XOR-swizzled slots) for ALL layers.
// W fragments are loaded straight global->VGPR (L2-resident; full-line reads).
// 3-pass split-bf16 MFMA core identical to the verified unfused kernel.
__global__ __launch_bounds__(512) void mlp_fused_kernel(
    const float* __restrict__ t,
    const float* __restrict__ Win, const float* __restrict__ bin,
    const unsigned short* __restrict__ WT,   // [5][512][KSTR]
    const float* __restrict__ bh,            // [5][512]
    const float* __restrict__ Wout, const float* __restrict__ bout,
    float* __restrict__ y) {
  __shared__ __align__(16) unsigned short act[32 * 1024];   // 64 KB
  const int tid  = threadIdx.x;
  const int lane = tid & 63, w = tid >> 6;      // 8 waves
  const int rl   = lane & 15, kgrp = lane >> 4;
  const int r0   = blockIdx.x * 32;
  const int cb   = w * 64;                      // wave's 64-col slice

  // ---- input layer: act = split(tanh(t*Win + bin)) ----
  {
    int row = tid >> 4;            // 0..31
    int kb  = tid & 15;
    float tv = t[r0 + row];
    int m = row & 7;
#pragma unroll
    for (int p = 0; p < 32; ++p) {
      int col = kb * 32 + p;
      float v = tanhf(tv * Win[col] + bin[col]);
      unsigned short h = f2bf(v);
      unsigned short lo = f2bf(v - bf2f(h));
      act[row * 1024 + kb * 64 + (((p >> 3) ^ m) * 8) + (p & 7)] = h;
      act[row * 1024 + kb * 64 + ((((p >> 3) | 4) ^ m) * 8) + (p & 7)] = lo;
    }
  }
  __syncthreads();

  // A-fragment LDS offsets (swizzled), per mi
  int aoff_h[2], aoff_l[2];
#pragma unroll
  for (int mi = 0; mi < 2; ++mi) {
    int row = mi * 16 + rl;
    aoff_h[mi] = row * 1024 + (kgrp ^ (row & 7)) * 8;
    aoff_l[mi] = row * 1024 + ((kgrp + 4) ^ (row & 7)) * 8;
  }

#define LOADB(BH, BL, KB)                                            \
  do {                                                               \
    _Pragma("unroll")                                                \
    for (int ni = 0; ni < 4; ++ni) {                                 \
      BH[ni] = *(const short8v*)(bp[ni] + (KB) * 64);                \
      BL[ni] = *(const short8v*)(bp[ni] + (KB) * 64 + 32);           \
    }                                                                \
  } while (0)

#define COMPUTE(KB, BH, BL)                                          \
  do {                                                               \
    short8v ah[2], al[2];                                            \
    _Pragma("unroll")                                                \
    for (int mi = 0; mi < 2; ++mi) {                                 \
      ah[mi] = *(const short8v*)&act[aoff_h[mi] + (KB) * 64];        \
      al[mi] = *(const short8v*)&act[aoff_l[mi] + (KB) * 64];        \
    }                                                                \
    _Pragma("unroll")                                                \
    for (int mi = 0; mi < 2; ++mi)                                   \
      _Pragma("unroll")                                              \
      for (int ni = 0; ni < 4; ++ni)                                 \
        acc[mi][ni] = __builtin_amdgcn_mfma_f32_16x16x32_bf16(       \
            ah[mi], BH[ni], acc[mi][ni], 0, 0, 0);                   \
    _Pragma("unroll")                                                \
    for (int mi = 0; mi < 2; ++mi)                                   \
      _Pragma("unroll")                                              \
      for (int ni = 0; ni < 4; ++ni)                                 \
        acc[mi][ni] = __builtin_amdgcn_mfma_f32_16x16x32_bf16(       \
            ah[mi], BL[ni], acc[mi][ni], 0, 0, 0);                   \
    _Pragma("unroll")                                                \
    for (int mi = 0; mi < 2; ++mi)                                   \
      _Pragma("unroll")                                              \
      for (int ni = 0; ni < 4; ++ni)                                 \
        acc[mi][ni] = __builtin_amdgcn_mfma_f32_16x16x32_bf16(       \
            al[mi], BH[ni], acc[mi][ni], 0, 0, 0);                   \
  } while (0)

  // ---- 5 hidden layers ----
  for (int l = 0; l < NHID; ++l) {
    const unsigned short* Wl = WT + (size_t)l * HDIM * KSTR;
    const float* bias = bh + l * HDIM;

    const unsigned short* bp[4];
#pragma unroll
    for (int ni = 0; ni < 4; ++ni)
      bp[ni] = Wl + (size_t)(cb + ni * 16 + rl) * KSTR + kgrp * 8;

    float4v acc[2][4];
#pragma unroll
    for (int mi = 0; mi < 2; ++mi)
#pragma unroll
      for (int ni = 0; ni < 4; ++ni) acc[mi][ni] = (float4v){0.f, 0.f, 0.f, 0.f};

    short8v bhc[4], blc[4], bhn[4], bln[4];
    LOADB(bhc, blc, 0);
    for (int kb = 0; kb < 16; kb += 2) {
      LOADB(bhn, bln, kb + 1);
      COMPUTE(kb, bhc, blc);
      if (kb + 2 < 16) LOADB(bhc, blc, kb + 2);
      COMPUTE(kb + 1, bhn, bln);
    }

    __syncthreads();     // all waves done reading act for this layer
    float bcol[4];
#pragma unroll
    for (int ni = 0; ni < 4; ++ni) bcol[ni] = bias[cb + ni * 16 + rl];
#pragma unroll
    for (int mi = 0; mi < 2; ++mi)
#pragma unroll
      for (int ni = 0; ni < 4; ++ni)
#pragma unroll
        for (int r = 0; r < 4; ++r) {
          int row = mi * 16 + kgrp * 4 + r;
          int col = cb + ni * 16 + rl;
          float v = tanhf(acc[mi][ni][r] + bcol[ni]);
          unsigned short h = f2bf(v);
          unsigned short lo = f2bf(v - bf2f(h));
          int kb2 = col >> 5, pos = col & 31, m = row & 7;
          act[row * 1024 + kb2 * 64 + (((pos >> 3) ^ m) * 8) + (pos & 7)] = h;
          act[row * 1024 + kb2 * 64 + ((((pos >> 3) | 4) ^ m) * 8) + (pos & 7)] = lo;
        }
    __syncthreads();     // act ready for next layer
  }

  // ---- output layer + softmax: rows w*4 .. w*4+3 per wave ----
#pragma unroll 1
  for (int rr = 0; rr < 4; ++rr) {
    int row = w * 4 + rr;
    int m = row & 7;
    int kb = lane >> 2, pg = lane & 3;
    short8v hv = *(const short8v*)&act[row * 1024 + kb * 64 + ((pg ^ m) * 8)];
    short8v lv = *(const short8v*)&act[row * 1024 + kb * 64 + (((pg | 4) ^ m) * 8)];
    const float* wrp = Wout + lane * 40;       // k = lane*8..+7, 5 cols each
    float a5[5] = {0.f, 0.f, 0.f, 0.f, 0.f};
#pragma unroll
    for (int e = 0; e < 8; ++e) {
      float h = bf2f((unsigned short)hv[e]) + bf2f((unsigned short)lv[e]);
#pragma unroll
      for (int c = 0; c < 5; ++c) a5[c] += h * wrp[e * 5 + c];
    }
#pragma unroll
    for (int c = 0; c < 5; ++c)
      for (int off = 32; off; off >>= 1) a5[c] += __shfl_down(a5[c], off);
    if (lane == 0) {
      float lg[5], mx = -1e30f;
#pragma unroll
      for (int c = 0; c < 5; ++c) { lg[c] = a5[c] + bout[c]; mx = fmaxf(mx, lg[c]); }
      float s = 0.f;
#pragma unroll
      for (int c = 0; c < 5; ++c) { lg[c] = expf(lg[c] - mx); s += lg[c]; }
      float inv = 1.f / s;
#pragma unroll
      for (int c = 0; c < 5; ++c) y[(r0 + row) * 5 + c] = lg[c] * inv;
    }
  }
#undef LOADB
#undef COMPUTE
}

// ---------------- Caputo prep: ws weights (double!) + dpsi ------------------
__global__ void prep_caputo_kernel(const float* __restrict__ z_alpha,
                                   const float* __restrict__ y,
                                   float* __restrict__ wsw,
                                   float* __restrict__ dpsi) {
  int g = blockIdx.x * blockDim.x + threadIdx.x;
  if (g < (N_PTS - 1) * 5) dpsi[g] = y[g + 5] - y[g];
  if (g < N_PTS - 1) {
    double z = (double)z_alpha[0];
    double alpha = 0.6 + 0.4 / (1.0 + exp(-z));
    double p = 1.0 - alpha;
    double w = pow((double)g + 1.0, p) - (g == 0 ? 0.0 : pow((double)g, p));
    wsw[g] = (float)w;
  }
}

// ---------------- Toeplitz conv partials (chunks of 512) --------------------
__global__ __launch_bounds__(256) void conv_kernel(
    const float* __restrict__ dpsi, const float* __restrict__ wsw,
    float* __restrict__ part) {
  __shared__ float dps[256][8];
  __shared__ float wsl[512];
  int tid = threadIdx.x;
  int r0  = blockIdx.x * 256;
  int ch  = blockIdx.y;
  int r   = r0 + tid;
  float acc[5] = {0.f, 0.f, 0.f, 0.f, 0.f};

  for (int t4 = 0; t4 < 2; ++t4) {
    int j0 = ch * 512 + t4 * 256;
    if (j0 > r0 + 254) break;             // block-uniform
    __syncthreads();
    {
      const float* dr = dpsi + (size_t)(j0 + tid) * 5;
      dps[tid][0] = dr[0]; dps[tid][1] = dr[1]; dps[tid][2] = dr[2];
      dps[tid][3] = dr[3]; dps[tid][4] = dr[4];
    }
    int base = r0 - j0 - 256;
#pragma unroll
    for (int s = 0; s < 2; ++s) {
      int i = tid + s * 256;
      int src = base + i;
      wsl[i] = (src >= 0 && src < N_PTS - 1) ? wsw[src] : 0.f;
    }
    __syncthreads();
    int widx = tid + 255;
#pragma unroll 4
    for (int jj = 0; jj < 256; ++jj) {
      float w = wsl[widx - jj];           // zero-padded outside valid lags
      float4 d4 = *(const float4*)&dps[jj][0];
      float d5 = dps[jj][4];
      acc[0] += w * d4.x; acc[1] += w * d4.y; acc[2] += w * d4.z;
      acc[3] += w * d4.w; acc[4] += w * d5;
    }
  }
  float* p = part + ((size_t)ch * N_PTS + r) * 5;
  p[0] = acc[0]; p[1] = acc[1]; p[2] = acc[2]; p[3] = acc[3]; p[4] = acc[4];
}

// ---------------- combine partials + residual + block reduce ----------------
__device__ __forceinline__ float softplusf_(float x) {
  return x > 20.f ? x : log1pf(expf(x));
}

__global__ void combine_kernel(const float* __restrict__ y,
                               const float* __restrict__ part,
                               const float* __restrict__ rb, const float* __restrict__ rs,
                               const float* __restrict__ rg, const float* __restrict__ rm,
                               const float* __restrict__ za,
                               float* __restrict__ bpart) {
  __shared__ float red[128];
  int tid = threadIdx.x;
  int row = blockIdx.x * 128 + tid;

  float beta  = softplusf_(rb[0]);
  float sigma = softplusf_(rs[0]);
  float gamma = softplusf_(rg[0]);
  float mu    = softplusf_(rm[0]);
  double z = (double)za[0];
  double alpha = 0.6 + 0.4 / (1.0 + exp(-z));
  float C = (float)(pow(0.1, -alpha) / tgamma(2.0 - alpha));

  float df[5];
  if (row == 0) {
    df[0] = df[1] = df[2] = df[3] = df[4] = 0.f;
  } else {
#pragma unroll
    for (int c = 0; c < 5; ++c) {
      float s = 0.f;
#pragma unroll
      for (int ch = 0; ch < NCH; ++ch)
        s += part[((size_t)ch * N_PTS + row) * 5 + c];
      df[c] = C * s;
    }
  }
  float yv[5];
#pragma unroll
  for (int c = 0; c < 5; ++c) yv[c] = y[row * 5 + c];
  float living = 1.f - yv[4];
  float inf_t = beta * yv[0] * yv[2] / living;
  float f[5];
  f[0] = -inf_t;
  f[1] = inf_t - sigma * yv[1];
  f[2] = sigma * yv[1] - (gamma + mu) * yv[2];
  f[3] = gamma * yv[2];
  f[4] = mu * yv[2];
  float s = 0.f;
#pragma unroll
  for (int c = 0; c < 5; ++c) { float d = df[c] - f[c]; s += d * d; }

  red[tid] = s;
  __syncthreads();
  for (int off = 64; off; off >>= 1) {
    if (tid < off) red[tid] += red[tid + off];
    __syncthreads();
  }
  if (tid == 0) bpart[blockIdx.x] = red[0];
}

__global__ void finish_kernel(const float* __restrict__ bpart, float* __restrict__ out) {
  if (threadIdx.x == 0) {
    float s = 0.f;
    for (int i = 0; i < 64; ++i) s += bpart[i];
    out[0] = s / (float)(N_PTS * 5);
  }
}

// ---------------- launch ----------------------------------------------------
extern "C" void kernel_launch(void* const* d_in, const int* in_sizes, int n_in,
                              void* d_out, int out_size, void* d_ws, size_t ws_size,
                              hipStream_t stream) {
  const float* t     = (const float*)d_in[0];
  const float* W_in  = (const float*)d_in[1];
  const float* b_in  = (const float*)d_in[2];
  const float* Wh    = (const float*)d_in[3];
  const float* bh    = (const float*)d_in[4];
  const float* W_out = (const float*)d_in[5];
  const float* b_out = (const float*)d_in[6];
  const float* rbta  = (const float*)d_in[7];
  const float* rsig  = (const float*)d_in[8];
  const float* rgam  = (const float*)d_in[9];
  const float* rmu   = (const float*)d_in[10];
  const float* zalp  = (const float*)d_in[11];

  char* wsb = (char*)d_ws;
  unsigned short* WT = (unsigned short*)(wsb + OFF_WT);
  float* y     = (float*)(wsb + OFF_Y);
  float* dpsi  = (float*)(wsb + OFF_DPSI);
  float* wsw   = (float*)(wsb + OFF_WSW);
  float* part  = (float*)(wsb + OFF_PART);
  float* bpart = (float*)(wsb + OFF_BPART);
  float* out   = (float*)d_out;

  // 0) W transpose + split into interleaved layout
  wprep_kernel<<<dim3(16, 16, 5), 256, 0, stream>>>(Wh, WT);

  // 1) fused MLP (input layer + 5 hidden + output/softmax)
  mlp_fused_kernel<<<N_PTS / 32, 512, 0, stream>>>(
      t, W_in, b_in, WT, bh, W_out, b_out, y);

  // 2) Caputo weights + dpsi
  prep_caputo_kernel<<<160, 256, 0, stream>>>(zalp, y, wsw, dpsi);

  // 3) Toeplitz conv partials
  conv_kernel<<<dim3(N_PTS / 256, NCH), 256, 0, stream>>>(dpsi, wsw, part);

  // 4) combine + residual + reduce
  combine_kernel<<<N_PTS / 128, 128, 0, stream>>>(y, part, rbta, rsig, rgam, rmu,
                                                  zalp, bpart);
  finish_kernel<<<1, 64, 0, stream>>>(bpart, out);
  (void)in_sizes; (void)n_in; (void)out_size; (void)ws_size;
}

// Round 9
// 166.930 us; speedup vs baseline: 1.3171x; 1.3171x over previous
//
#include <hip/hip_runtime.h>
#include <math.h>

typedef short short8v __attribute__((ext_vector_type(8)));
typedef float float4v __attribute__((ext_vector_type(4)));

#define N_PTS 8192
#define HDIM  512
#define NHID  5
#define KSTR  1024   // shorts per activation/weight row: 16 kb x (32 hi + 32 lo)
#define NCH   16     // conv j-chunks of 512

// byte offsets in workspace
#define OFF_XA    0ull
#define OFF_XB    16777216ull
#define OFF_WT    33554432ull
#define OFF_Y     38797312ull
#define OFF_DPSI  38961152ull
#define OFF_WSW   39124992ull
#define OFF_PART  39157760ull
#define OFF_BPART 41779200ull

__device__ __forceinline__ unsigned short f2bf(float x) {
  unsigned u = __builtin_bit_cast(unsigned, x);
  u += 0x7FFFu + ((u >> 16) & 1u);
  return (unsigned short)(u >> 16);
}
__device__ __forceinline__ float bf2f(unsigned short h) {
  unsigned u = ((unsigned)h) << 16;
  return __builtin_bit_cast(float, u);
}

#define GLOAD16(gsrc, ldst) \
  __builtin_amdgcn_global_load_lds( \
      (const __attribute__((address_space(1))) void*)(gsrc), \
      (__attribute__((address_space(3))) void*)(ldst), 16, 0, 0)

// ---------------- W prep: transpose + split, interleaved hi|lo layout -------
// Wh [5][512(k)][512(n)] f32 -> WT [5][512(n)][16 kb][32 hi | 32 lo] bf16
__global__ void wprep_kernel(const float* __restrict__ Wh,
                             unsigned short* __restrict__ WT) {
  __shared__ float tile[32][33];
  int l = blockIdx.z;
  int kb = blockIdx.x;                 // k-tile of 32
  int n0 = blockIdx.y * 32;
  int j = threadIdx.x & 31, i8 = threadIdx.x >> 5;
  const float* W = Wh + (size_t)l * HDIM * HDIM;
#pragma unroll
  for (int q = 0; q < 4; ++q)
    tile[i8 + 8 * q][j] = W[(size_t)(kb * 32 + i8 + 8 * q) * HDIM + n0 + j];
  __syncthreads();
#pragma unroll
  for (int q = 0; q < 4; ++q) {
    int n = n0 + i8 + 8 * q;           // output row (col of W)
    float v = tile[j][i8 + 8 * q];     // W[kb*32+j][n]
    unsigned short h = f2bf(v);
    unsigned short lo = f2bf(v - bf2f(h));
    size_t o = ((size_t)l * HDIM + n) * KSTR + kb * 64 + j;
    WT[o] = h; WT[o + 32] = lo;
  }
}

// ---------------- layer 0: h = tanh(t*W_in + b_in), split, interleaved ------
__global__ void layer0_kernel(const float* __restrict__ t,
                              const float* __restrict__ Win,
                              const float* __restrict__ bin,
                              unsigned short* __restrict__ X) {
  int gid = blockIdx.x * blockDim.x + threadIdx.x;
  int row = gid >> 7;
  int jq  = (gid & 127) << 2;          // k = jq..jq+3
  float tv = t[row];
  float4 w = *(const float4*)(Win + jq);
  float4 b = *(const float4*)(bin + jq);
  float v[4];
  v[0] = tanhf(tv * w.x + b.x); v[1] = tanhf(tv * w.y + b.y);
  v[2] = tanhf(tv * w.z + b.z); v[3] = tanhf(tv * w.w + b.w);
  ushort4 h4, l4;
  h4.x = f2bf(v[0]); l4.x = f2bf(v[0] - bf2f(h4.x));
  h4.y = f2bf(v[1]); l4.y = f2bf(v[1] - bf2f(h4.y));
  h4.z = f2bf(v[2]); l4.z = f2bf(v[2] - bf2f(h4.z));
  h4.w = f2bf(v[3]); l4.w = f2bf(v[3] - bf2f(h4.w));
  size_t o = (size_t)row * KSTR + (jq >> 5) * 64 + (jq & 31);
  *(ushort4*)(X + o) = h4;
  *(ushort4*)(X + o + 32) = l4;
}

// ---------------- split-bf16 MFMA GEMM + tanh + re-split --------------------
// tile 128x128, BK=32, 4 waves (2x2), wave tile 64x64 (M4/N4)
// grid (64,4) = 256 blocks; 2-buffer LDS (64 KB) -> 2 blocks/CU.
// 2-phase pipeline: stage(kt+1) issued BEFORE compute(kt); vmcnt(0)+barrier
// once per kt (T3-minimum recipe; 2 blocks/CU cover the drain).
// LDS row = 128B = 8 slots of 16B; swizzle: slot ^= (row & 7) on BOTH sides.
__global__ __launch_bounds__(256) void gemm_split_kernel(
    const unsigned short* __restrict__ A,    // [8192][KSTR]
    const unsigned short* __restrict__ Bt,   // [512][KSTR]
    const float* __restrict__ bias,
    unsigned short* __restrict__ C) {        // [8192][KSTR]
  // per buffer (shorts): A 0..8191 (128 rows x 64), B 8192..16383 (128 cols x 64)
  __shared__ __align__(16) short lds[2][16384];   // 64 KB
  const int tid = threadIdx.x;
  const int lane = tid & 63, w = tid >> 6;
  const int wr = w >> 1, wc = w & 1;             // 2x2 wave grid
  const int r0 = blockIdx.x * 128, c0 = blockIdx.y * 128;
  const int rl = lane & 15, kgrp = lane >> 4;

  float4v acc[4][4];
#pragma unroll
  for (int i = 0; i < 4; ++i)
#pragma unroll
    for (int j = 0; j < 4; ++j) acc[i][j] = (float4v){0.f, 0.f, 0.f, 0.f};

  auto stage = [&](int b, int kt) {
    const int kbase = kt * 64;
    // A tile: 128 rows x 8 chunks = 1024 chunks, 4 per thread
#pragma unroll
    for (int i = 0; i < 4; ++i) {
      int c = i * 256 + tid;
      int row = c >> 3, m = c & 7;
      int gs = m ^ (row & 7);          // inverse-swizzled global slot
      GLOAD16(A + (size_t)(r0 + row) * KSTR + kbase + gs * 8,
              &lds[b][(i * 256 + w * 64) * 8]);
    }
    // B tile: 128 cols x 8 chunks = 1024 chunks, 4 per thread
#pragma unroll
    for (int i = 0; i < 4; ++i) {
      int c = i * 256 + tid;
      int col = c >> 3, m = c & 7;
      int gs = m ^ (col & 7);
      GLOAD16(Bt + (size_t)(c0 + col) * KSTR + kbase + gs * 8,
              &lds[b][8192 + (i * 256 + w * 64) * 8]);
    }
  };

  stage(0, 0);
  asm volatile("s_waitcnt vmcnt(0)" ::: "memory");
  __builtin_amdgcn_s_barrier();
  asm volatile("" ::: "memory");

#pragma unroll 1
  for (int kt = 0; kt < 16; ++kt) {
    if (kt < 15) stage((kt + 1) & 1, kt + 1);     // issue next-tile loads first
    const short* bufc = lds[kt & 1];
    short8v ahi[4], alo[4], bhi[4], blo[4];
#pragma unroll
    for (int mi = 0; mi < 4; ++mi) {
      int row = wr * 64 + mi * 16 + rl;
      int sh = kgrp ^ (row & 7);
      int sl = (kgrp + 4) ^ (row & 7);
      ahi[mi] = *(const short8v*)&bufc[row * 64 + sh * 8];
      alo[mi] = *(const short8v*)&bufc[row * 64 + sl * 8];
    }
#pragma unroll
    for (int ni = 0; ni < 4; ++ni) {
      int col = wc * 64 + ni * 16 + rl;
      int sh = kgrp ^ (col & 7);
      int sl = (kgrp + 4) ^ (col & 7);
      bhi[ni] = *(const short8v*)&bufc[8192 + col * 64 + sh * 8];
      blo[ni] = *(const short8v*)&bufc[8192 + col * 64 + sl * 8];
    }
    __builtin_amdgcn_s_setprio(1);
#pragma unroll
    for (int mi = 0; mi < 4; ++mi)
#pragma unroll
      for (int ni = 0; ni < 4; ++ni)
        acc[mi][ni] = __builtin_amdgcn_mfma_f32_16x16x32_bf16(ahi[mi], bhi[ni], acc[mi][ni], 0, 0, 0);
#pragma unroll
    for (int mi = 0; mi < 4; ++mi)
#pragma unroll
      for (int ni = 0; ni < 4; ++ni)
        acc[mi][ni] = __builtin_amdgcn_mfma_f32_16x16x32_bf16(ahi[mi], blo[ni], acc[mi][ni], 0, 0, 0);
#pragma unroll
    for (int mi = 0; mi < 4; ++mi)
#pragma unroll
      for (int ni = 0; ni < 4; ++ni)
        acc[mi][ni] = __builtin_amdgcn_mfma_f32_16x16x32_bf16(alo[mi], bhi[ni], acc[mi][ni], 0, 0, 0);
    __builtin_amdgcn_s_setprio(0);
    if (kt < 15) {
      asm volatile("s_waitcnt vmcnt(0)" ::: "memory");  // next tile staged
      __builtin_amdgcn_s_barrier();
      asm volatile("" ::: "memory");
    }
  }

  float bcol[4];
#pragma unroll
  for (int ni = 0; ni < 4; ++ni) bcol[ni] = bias[c0 + wc * 64 + ni * 16 + rl];
#pragma unroll
  for (int mi = 0; mi < 4; ++mi)
#pragma unroll
    for (int ni = 0; ni < 4; ++ni)
#pragma unroll
      for (int r = 0; r < 4; ++r) {
        int row = r0 + wr * 64 + mi * 16 + kgrp * 4 + r;
        int col = c0 + wc * 64 + ni * 16 + rl;
        float v = tanhf(acc[mi][ni][r] + bcol[ni]);
        unsigned short h = f2bf(v);
        unsigned short lo = f2bf(v - bf2f(h));
        size_t o = (size_t)row * KSTR + (col >> 5) * 64 + (col & 31);
        C[o] = h; C[o + 32] = lo;
      }
}

// ---------------- output layer: y = softmax(h @ W_out + b_out) --------------
__global__ void outlayer_kernel(const unsigned short* __restrict__ X,
                                const float* __restrict__ Wout,
                                const float* __restrict__ bout,
                                float* __restrict__ y) {
  int wid  = threadIdx.x >> 6;
  int lane = threadIdx.x & 63;
  int row  = blockIdx.x * 4 + wid;
  // lane handles k = lane*8 .. lane*8+7
  size_t o = (size_t)row * KSTR + (lane >> 2) * 64 + (lane & 3) * 8;
  short8v hv = *(const short8v*)(X + o);
  short8v lv = *(const short8v*)(X + o + 32);
  const float* wrp = Wout + lane * 40;
  float acc[5] = {0.f, 0.f, 0.f, 0.f, 0.f};
#pragma unroll
  for (int e = 0; e < 8; ++e) {
    float h = bf2f((unsigned short)hv[e]) + bf2f((unsigned short)lv[e]);
#pragma unroll
    for (int c = 0; c < 5; ++c) acc[c] += h * wrp[e * 5 + c];
  }
#pragma unroll
  for (int c = 0; c < 5; ++c)
    for (int off = 32; off; off >>= 1) acc[c] += __shfl_down(acc[c], off);
  if (lane == 0) {
    float l[5], m = -1e30f;
#pragma unroll
    for (int c = 0; c < 5; ++c) { l[c] = acc[c] + bout[c]; m = fmaxf(m, l[c]); }
    float s = 0.f;
#pragma unroll
    for (int c = 0; c < 5; ++c) { l[c] = expf(l[c] - m); s += l[c]; }
    float inv = 1.f / s;
#pragma unroll
    for (int c = 0; c < 5; ++c) y[row * 5 + c] = l[c] * inv;
  }
}

// ---------------- Caputo prep: ws weights (double!) + dpsi ------------------
__global__ void prep_caputo_kernel(const float* __restrict__ z_alpha,
                                   const float* __restrict__ y,
                                   float* __restrict__ wsw,
                                   float* __restrict__ dpsi) {
  int g = blockIdx.x * blockDim.x + threadIdx.x;
  if (g < (N_PTS - 1) * 5) dpsi[g] = y[g + 5] - y[g];
  if (g < N_PTS - 1) {
    double z = (double)z_alpha[0];
    double alpha = 0.6 + 0.4 / (1.0 + exp(-z));
    double p = 1.0 - alpha;
    double w = pow((double)g + 1.0, p) - (g == 0 ? 0.0 : pow((double)g, p));
    wsw[g] = (float)w;
  }
}

// ---------------- Toeplitz conv partials (chunks of 512) --------------------
__global__ __launch_bounds__(256) void conv_kernel(
    const float* __restrict__ dpsi, const float* __restrict__ wsw,
    float* __restrict__ part) {
  __shared__ float dps[256][8];
  __shared__ float wsl[512];
  int tid = threadIdx.x;
  int r0  = blockIdx.x * 256;
  int ch  = blockIdx.y;
  int r   = r0 + tid;
  float acc[5] = {0.f, 0.f, 0.f, 0.f, 0.f};

  for (int t4 = 0; t4 < 2; ++t4) {
    int j0 = ch * 512 + t4 * 256;
    if (j0 > r0 + 254) break;             // block-uniform
    __syncthreads();
    {
      const float* dr = dpsi + (size_t)(j0 + tid) * 5;
      dps[tid][0] = dr[0]; dps[tid][1] = dr[1]; dps[tid][2] = dr[2];
      dps[tid][3] = dr[3]; dps[tid][4] = dr[4];
    }
    int base = r0 - j0 - 256;
#pragma unroll
    for (int s = 0; s < 2; ++s) {
      int i = tid + s * 256;
      int src = base + i;
      wsl[i] = (src >= 0 && src < N_PTS - 1) ? wsw[src] : 0.f;
    }
    __syncthreads();
    int widx = tid + 255;
#pragma unroll 4
    for (int jj = 0; jj < 256; ++jj) {
      float w = wsl[widx - jj];           // zero-padded outside valid lags
      float4 d4 = *(const float4*)&dps[jj][0];
      float d5 = dps[jj][4];
      acc[0] += w * d4.x; acc[1] += w * d4.y; acc[2] += w * d4.z;
      acc[3] += w * d4.w; acc[4] += w * d5;
    }
  }
  float* p = part + ((size_t)ch * N_PTS + r) * 5;
  p[0] = acc[0]; p[1] = acc[1]; p[2] = acc[2]; p[3] = acc[3]; p[4] = acc[4];
}

// ---------------- combine partials + residual + block reduce ----------------
__device__ __forceinline__ float softplusf_(float x) {
  return x > 20.f ? x : log1pf(expf(x));
}

__global__ void combine_kernel(const float* __restrict__ y,
                               const float* __restrict__ part,
                               const float* __restrict__ rb, const float* __restrict__ rs,
                               const float* __restrict__ rg, const float* __restrict__ rm,
                               const float* __restrict__ za,
                               float* __restrict__ bpart) {
  __shared__ float red[128];
  int tid = threadIdx.x;
  int row = blockIdx.x * 128 + tid;

  float beta  = softplusf_(rb[0]);
  float sigma = softplusf_(rs[0]);
  float gamma = softplusf_(rg[0]);
  float mu    = softplusf_(rm[0]);
  double z = (double)za[0];
  double alpha = 0.6 + 0.4 / (1.0 + exp(-z));
  float C = (float)(pow(0.1, -alpha) / tgamma(2.0 - alpha));

  float df[5];
  if (row == 0) {
    df[0] = df[1] = df[2] = df[3] = df[4] = 0.f;
  } else {
#pragma unroll
    for (int c = 0; c < 5; ++c) {
      float s = 0.f;
#pragma unroll
      for (int ch = 0; ch < NCH; ++ch)
        s += part[((size_t)ch * N_PTS + row) * 5 + c];
      df[c] = C * s;
    }
  }
  float yv[5];
#pragma unroll
  for (int c = 0; c < 5; ++c) yv[c] = y[row * 5 + c];
  float living = 1.f - yv[4];
  float inf_t = beta * yv[0] * yv[2] / living;
  float f[5];
  f[0] = -inf_t;
  f[1] = inf_t - sigma * yv[1];
  f[2] = sigma * yv[1] - (gamma + mu) * yv[2];
  f[3] = gamma * yv[2];
  f[4] = mu * yv[2];
  float s = 0.f;
#pragma unroll
  for (int c = 0; c < 5; ++c) { float d = df[c] - f[c]; s += d * d; }

  red[tid] = s;
  __syncthreads();
  for (int off = 64; off; off >>= 1) {
    if (tid < off) red[tid] += red[tid + off];
    __syncthreads();
  }
  if (tid == 0) bpart[blockIdx.x] = red[0];
}

__global__ void finish_kernel(const float* __restrict__ bpart, float* __restrict__ out) {
  if (threadIdx.x == 0) {
    float s = 0.f;
    for (int i = 0; i < 64; ++i) s += bpart[i];
    out[0] = s / (float)(N_PTS * 5);
  }
}

// ---------------- launch ----------------------------------------------------
extern "C" void kernel_launch(void* const* d_in, const int* in_sizes, int n_in,
                              void* d_out, int out_size, void* d_ws, size_t ws_size,
                              hipStream_t stream) {
  const float* t     = (const float*)d_in[0];
  const float* W_in  = (const float*)d_in[1];
  const float* b_in  = (const float*)d_in[2];
  const float* Wh    = (const float*)d_in[3];
  const float* bh    = (const float*)d_in[4];
  const float* W_out = (const float*)d_in[5];
  const float* b_out = (const float*)d_in[6];
  const float* rbta  = (const float*)d_in[7];
  const float* rsig  = (const float*)d_in[8];
  const float* rgam  = (const float*)d_in[9];
  const float* rmu   = (const float*)d_in[10];
  const float* zalp  = (const float*)d_in[11];

  char* wsb = (char*)d_ws;
  unsigned short* XA = (unsigned short*)(wsb + OFF_XA);
  unsigned short* XB = (unsigned short*)(wsb + OFF_XB);
  unsigned short* WT = (unsigned short*)(wsb + OFF_WT);
  float* y     = (float*)(wsb + OFF_Y);
  float* dpsi  = (float*)(wsb + OFF_DPSI);
  float* wsw   = (float*)(wsb + OFF_WSW);
  float* part  = (float*)(wsb + OFF_PART);
  float* bpart = (float*)(wsb + OFF_BPART);
  float* out   = (float*)d_out;

  // 0) W transpose + split into interleaved layout
  wprep_kernel<<<dim3(16, 16, 5), 256, 0, stream>>>(Wh, WT);

  // 1) first layer
  layer0_kernel<<<N_PTS * 128 / 256, 256, 0, stream>>>(t, W_in, b_in, XA);

  // 2) 5 hidden layers, ping-pong
  for (int l = 0; l < NHID; ++l) {
    const unsigned short* in = (l & 1) ? XB : XA;
    unsigned short*      oub = (l & 1) ? XA : XB;
    gemm_split_kernel<<<dim3(N_PTS / 128, HDIM / 128), 256, 0, stream>>>(
        in, WT + (size_t)l * HDIM * KSTR, bh + (size_t)l * HDIM, oub);
  }
  // NHID=5 -> final activations in XB

  // 3) output layer + softmax
  outlayer_kernel<<<N_PTS / 4, 256, 0, stream>>>(XB, W_out, b_out, y);

  // 4) Caputo weights + dpsi (one kernel)
  prep_caputo_kernel<<<160, 256, 0, stream>>>(zalp, y, wsw, dpsi);

  // 5) Toeplitz conv partials
  conv_kernel<<<dim3(N_PTS / 256, NCH), 256, 0, stream>>>(dpsi, wsw, part);

  // 6) combine + residual + reduce
  combine_kernel<<<N_PTS / 128, 128, 0, stream>>>(y, part, rbta, rsig, rgam, rmu,
                                                  zalp, bpart);
  finish_kernel<<<1, 64, 0, stream>>>(bpart, out);
  (void)in_sizes; (void)n_in; (void)out_size; (void)ws_size;
}

// Round 10
// 158.939 us; speedup vs baseline: 1.3833x; 1.0503x over previous
//
#include <hip/hip_runtime.h>
#include <math.h>

typedef short short8v __attribute__((ext_vector_type(8)));
typedef float float4v __attribute__((ext_vector_type(4)));

#define N_PTS 8192
#define HDIM  512
#define NHID  5
#define KSTR  1024   // shorts per weight row: 16 kb x (32 hi + 32 lo)
#define NCH   16     // conv j-chunks of 512

// byte offsets in workspace
#define OFF_WT    33554432ull
#define OFF_Y     38797312ull
#define OFF_DPSI  38961152ull
#define OFF_WSW   39124992ull
#define OFF_PART  39157760ull
#define OFF_BPART 41779200ull

__device__ __forceinline__ unsigned short f2bf(float x) {
  unsigned u = __builtin_bit_cast(unsigned, x);
  u += 0x7FFFu + ((u >> 16) & 1u);
  return (unsigned short)(u >> 16);
}
__device__ __forceinline__ float bf2f(unsigned short h) {
  unsigned u = ((unsigned)h) << 16;
  return __builtin_bit_cast(float, u);
}

#define GLOAD16(gsrc, ldst) \
  __builtin_amdgcn_global_load_lds( \
      (const __attribute__((address_space(1))) void*)(gsrc), \
      (__attribute__((address_space(3))) void*)(ldst), 16, 0, 0)

// ---------------- W prep: transpose + split, interleaved hi|lo layout -------
// Wh [5][512(k)][512(n)] f32 -> WT [5][512(n)][16 kb][32 hi | 32 lo] bf16
__global__ void wprep_kernel(const float* __restrict__ Wh,
                             unsigned short* __restrict__ WT) {
  __shared__ float tile[32][33];
  int l = blockIdx.z;
  int kb = blockIdx.x;                 // k-tile of 32
  int n0 = blockIdx.y * 32;
  int j = threadIdx.x & 31, i8 = threadIdx.x >> 5;
  const float* W = Wh + (size_t)l * HDIM * HDIM;
#pragma unroll
  for (int q = 0; q < 4; ++q)
    tile[i8 + 8 * q][j] = W[(size_t)(kb * 32 + i8 + 8 * q) * HDIM + n0 + j];
  __syncthreads();
#pragma unroll
  for (int q = 0; q < 4; ++q) {
    int n = n0 + i8 + 8 * q;           // output row (col of W)
    float v = tile[j][i8 + 8 * q];     // W[kb*32+j][n]
    unsigned short h = f2bf(v);
    unsigned short lo = f2bf(v - bf2f(h));
    size_t o = ((size_t)l * HDIM + n) * KSTR + kb * 64 + j;
    WT[o] = h; WT[o + 32] = lo;
  }
}

// ---------------- fused MLP -------------------------------------------------
// 256 blocks (1/CU) x 512 thr (8 waves).  Block owns 32 rows; act panel
// 32x512 (split bf16 hi|lo, XOR-swizzled slots) stays in LDS all 6 layers.
// B (=W^T) streamed via global_load_lds into 3 x 32KB buffers, 2-deep
// prefetch with counted vmcnt(4) (r7's proven schedule).  Wave tile 32x32
// (mi2 x ni2), chunks of 256 cols (cp=0,1).  3-pass split-bf16 MFMA core,
// K order and pass order bit-identical to the verified unfused GEMM.
__global__ __launch_bounds__(512) void mlp_fused_kernel(
    const float* __restrict__ t,
    const float* __restrict__ Win, const float* __restrict__ bin,
    const unsigned short* __restrict__ WT,   // [5][512][KSTR]
    const float* __restrict__ bh,            // [5][512]
    const float* __restrict__ Wout, const float* __restrict__ bout,
    float* __restrict__ y) {
  __shared__ __align__(16) unsigned short smem[81920];   // 160 KB exact
  unsigned short* act = smem;                 // 32 rows x 1024 shorts (64 KB)
  short* Bb = (short*)(smem + 32768);         // 3 x 16384 shorts (96 KB)

  const int tid  = threadIdx.x;
  const int lane = tid & 63, w = tid >> 6;    // w = wave = col group (0..7)
  const int rl   = lane & 15, kgrp = lane >> 4;
  const int r0   = blockIdx.x * 32;

  // stage B tile for global step gt: layer gt>>5, chunk (gt>>4)&1, kt gt&15
  auto stageB = [&](int gt) {
    int st = gt & 31;
    int cpt = st >> 4, ktt = st & 15;
    const unsigned short* Wl = WT + (size_t)(gt >> 5) * HDIM * KSTR;
    short* dstb = Bb + (gt % 3) * 16384;
#pragma unroll
    for (int i = 0; i < 4; ++i) {
      int c = i * 512 + tid;
      int col = c >> 3, m = c & 7;
      int gs = m ^ (col & 7);                 // inverse-swizzled source slot
      GLOAD16(Wl + (size_t)(cpt * 256 + col) * KSTR + ktt * 64 + gs * 8,
              dstb + c * 8);
    }
  };

  stageB(0);
  stageB(1);

  // ---- input layer: act = split(tanh(t*Win + bin)) (r8-verified) ----
  {
    int row = tid >> 4, kb = tid & 15, m = row & 7;
    float tv = t[r0 + row];
#pragma unroll
    for (int p = 0; p < 32; ++p) {
      int col = kb * 32 + p;
      float v = tanhf(tv * Win[col] + bin[col]);
      unsigned short h = f2bf(v);
      unsigned short lo = f2bf(v - bf2f(h));
      act[row * 1024 + kb * 64 + (((p >> 3) ^ m) * 8) + (p & 7)] = h;
      act[row * 1024 + kb * 64 + ((((p >> 3) | 4) ^ m) * 8) + (p & 7)] = lo;
    }
  }
  asm volatile("s_waitcnt vmcnt(4) lgkmcnt(0)" ::: "memory");  // buf0 staged
  __builtin_amdgcn_s_barrier();
  asm volatile("" ::: "memory");

  // ---- 5 hidden layers ----
#pragma unroll 1
  for (int l = 0; l < NHID; ++l) {
    float4v acc[2][2][2];                     // [cp][mi][ni]
#pragma unroll
    for (int a = 0; a < 2; ++a)
#pragma unroll
      for (int b = 0; b < 2; ++b)
#pragma unroll
        for (int c = 0; c < 2; ++c) acc[a][b][c] = (float4v){0.f, 0.f, 0.f, 0.f};

#pragma unroll
    for (int cp = 0; cp < 2; ++cp) {
#pragma unroll 1
      for (int kt = 0; kt < 16; ++kt) {
        int g = l * 32 + cp * 16 + kt;
        bool pf = (g + 2) < NHID * 32;
        if (pf) stageB(g + 2);                // 2-deep prefetch
        const short* Bt = Bb + (g % 3) * 16384;

        short8v ahi[2], alo[2], bhi[2], blo[2];
#pragma unroll
        for (int mi = 0; mi < 2; ++mi) {
          int row = mi * 16 + rl;
          int base = row * 1024 + kt * 64;
          ahi[mi] = *(const short8v*)&act[base + (kgrp ^ (row & 7)) * 8];
          alo[mi] = *(const short8v*)&act[base + ((kgrp + 4) ^ (row & 7)) * 8];
        }
#pragma unroll
        for (int ni = 0; ni < 2; ++ni) {
          int colt = w * 32 + ni * 16 + rl;
          bhi[ni] = *(const short8v*)&Bt[colt * 64 + (kgrp ^ (colt & 7)) * 8];
          blo[ni] = *(const short8v*)&Bt[colt * 64 + ((kgrp + 4) ^ (colt & 7)) * 8];
        }
        __builtin_amdgcn_s_setprio(1);
#pragma unroll
        for (int mi = 0; mi < 2; ++mi)
#pragma unroll
          for (int ni = 0; ni < 2; ++ni)
            acc[cp][mi][ni] = __builtin_amdgcn_mfma_f32_16x16x32_bf16(
                ahi[mi], bhi[ni], acc[cp][mi][ni], 0, 0, 0);
#pragma unroll
        for (int mi = 0; mi < 2; ++mi)
#pragma unroll
          for (int ni = 0; ni < 2; ++ni)
            acc[cp][mi][ni] = __builtin_amdgcn_mfma_f32_16x16x32_bf16(
                ahi[mi], blo[ni], acc[cp][mi][ni], 0, 0, 0);
#pragma unroll
        for (int mi = 0; mi < 2; ++mi)
#pragma unroll
          for (int ni = 0; ni < 2; ++ni)
            acc[cp][mi][ni] = __builtin_amdgcn_mfma_f32_16x16x32_bf16(
                alo[mi], bhi[ni], acc[cp][mi][ni], 0, 0, 0);
        __builtin_amdgcn_s_setprio(0);
        if (pf) asm volatile("s_waitcnt vmcnt(4)" ::: "memory");
        else    asm volatile("s_waitcnt vmcnt(0)" ::: "memory");
        __builtin_amdgcn_s_barrier();
        asm volatile("" ::: "memory");
      }
    }

    // epilogue: tanh + re-split, write act in place (reads all done above)
#pragma unroll
    for (int cp = 0; cp < 2; ++cp)
#pragma unroll
      for (int mi = 0; mi < 2; ++mi)
#pragma unroll
        for (int ni = 0; ni < 2; ++ni) {
          int colg = cp * 256 + w * 32 + ni * 16 + rl;
          float bc = bh[l * HDIM + colg];
          int kb2 = colg >> 5, pos = colg & 31;
#pragma unroll
          for (int r = 0; r < 4; ++r) {
            int row = mi * 16 + kgrp * 4 + r;
            int m = row & 7;
            float v = tanhf(acc[cp][mi][ni][r] + bc);
            unsigned short h = f2bf(v);
            unsigned short lo = f2bf(v - bf2f(h));
            act[row * 1024 + kb2 * 64 + (((pos >> 3) ^ m) * 8) + (pos & 7)] = h;
            act[row * 1024 + kb2 * 64 + ((((pos >> 3) | 4) ^ m) * 8) + (pos & 7)] = lo;
          }
        }
    asm volatile("s_waitcnt lgkmcnt(0)" ::: "memory");  // act writes visible
    __builtin_amdgcn_s_barrier();
    asm volatile("" ::: "memory");
  }

  // ---- output layer + softmax (r8-verified): rows w*4..w*4+3 per wave ----
#pragma unroll 1
  for (int rr = 0; rr < 4; ++rr) {
    int row = w * 4 + rr;
    int m = row & 7;
    int kb = lane >> 2, pg = lane & 3;
    short8v hv = *(const short8v*)&act[row * 1024 + kb * 64 + ((pg ^ m) * 8)];
    short8v lv = *(const short8v*)&act[row * 1024 + kb * 64 + (((pg | 4) ^ m) * 8)];
    const float* wrp = Wout + lane * 40;      // k = lane*8..+7, 5 cols each
    float a5[5] = {0.f, 0.f, 0.f, 0.f, 0.f};
#pragma unroll
    for (int e = 0; e < 8; ++e) {
      float h = bf2f((unsigned short)hv[e]) + bf2f((unsigned short)lv[e]);
#pragma unroll
      for (int c = 0; c < 5; ++c) a5[c] += h * wrp[e * 5 + c];
    }
#pragma unroll
    for (int c = 0; c < 5; ++c)
      for (int off = 32; off; off >>= 1) a5[c] += __shfl_down(a5[c], off);
    if (lane == 0) {
      float lg[5], mx = -1e30f;
#pragma unroll
      for (int c = 0; c < 5; ++c) { lg[c] = a5[c] + bout[c]; mx = fmaxf(mx, lg[c]); }
      float s = 0.f;
#pragma unroll
      for (int c = 0; c < 5; ++c) { lg[c] = expf(lg[c] - mx); s += lg[c]; }
      float inv = 1.f / s;
#pragma unroll
      for (int c = 0; c < 5; ++c) y[(r0 + row) * 5 + c] = lg[c] * inv;
    }
  }
}

// ---------------- Caputo prep: ws weights (double!) + dpsi ------------------
__global__ void prep_caputo_kernel(const float* __restrict__ z_alpha,
                                   const float* __restrict__ y,
                                   float* __restrict__ wsw,
                                   float* __restrict__ dpsi) {
  int g = blockIdx.x * blockDim.x + threadIdx.x;
  if (g < (N_PTS - 1) * 5) dpsi[g] = y[g + 5] - y[g];
  if (g < N_PTS - 1) {
    double z = (double)z_alpha[0];
    double alpha = 0.6 + 0.4 / (1.0 + exp(-z));
    double p = 1.0 - alpha;
    double w = pow((double)g + 1.0, p) - (g == 0 ? 0.0 : pow((double)g, p));
    wsw[g] = (float)w;
  }
}

// ---------------- Toeplitz conv partials (chunks of 512) --------------------
__global__ __launch_bounds__(256) void conv_kernel(
    const float* __restrict__ dpsi, const float* __restrict__ wsw,
    float* __restrict__ part) {
  __shared__ float dps[256][8];
  __shared__ float wsl[512];
  int tid = threadIdx.x;
  int r0  = blockIdx.x * 256;
  int ch  = blockIdx.y;
  int r   = r0 + tid;
  float acc[5] = {0.f, 0.f, 0.f, 0.f, 0.f};

  for (int t4 = 0; t4 < 2; ++t4) {
    int j0 = ch * 512 + t4 * 256;
    if (j0 > r0 + 254) break;             // block-uniform
    __syncthreads();
    {
      const float* dr = dpsi + (size_t)(j0 + tid) * 5;
      dps[tid][0] = dr[0]; dps[tid][1] = dr[1]; dps[tid][2] = dr[2];
      dps[tid][3] = dr[3]; dps[tid][4] = dr[4];
    }
    int base = r0 - j0 - 256;
#pragma unroll
    for (int s = 0; s < 2; ++s) {
      int i = tid + s * 256;
      int src = base + i;
      wsl[i] = (src >= 0 && src < N_PTS - 1) ? wsw[src] : 0.f;
    }
    __syncthreads();
    int widx = tid + 255;
#pragma unroll 4
    for (int jj = 0; jj < 256; ++jj) {
      float w = wsl[widx - jj];           // zero-padded outside valid lags
      float4 d4 = *(const float4*)&dps[jj][0];
      float d5 = dps[jj][4];
      acc[0] += w * d4.x; acc[1] += w * d4.y; acc[2] += w * d4.z;
      acc[3] += w * d4.w; acc[4] += w * d5;
    }
  }
  float* p = part + ((size_t)ch * N_PTS + r) * 5;
  p[0] = acc[0]; p[1] = acc[1]; p[2] = acc[2]; p[3] = acc[3]; p[4] = acc[4];
}

// ---------------- combine partials + residual + block reduce ----------------
__device__ __forceinline__ float softplusf_(float x) {
  return x > 20.f ? x : log1pf(expf(x));
}

__global__ void combine_kernel(const float* __restrict__ y,
                               const float* __restrict__ part,
                               const float* __restrict__ rb, const float* __restrict__ rs,
                               const float* __restrict__ rg, const float* __restrict__ rm,
                               const float* __restrict__ za,
                               float* __restrict__ bpart) {
  __shared__ float red[128];
  int tid = threadIdx.x;
  int row = blockIdx.x * 128 + tid;

  float beta  = softplusf_(rb[0]);
  float sigma = softplusf_(rs[0]);
  float gamma = softplusf_(rg[0]);
  float mu    = softplusf_(rm[0]);
  double z = (double)za[0];
  double alpha = 0.6 + 0.4 / (1.0 + exp(-z));
  float C = (float)(pow(0.1, -alpha) / tgamma(2.0 - alpha));

  float df[5];
  if (row == 0) {
    df[0] = df[1] = df[2] = df[3] = df[4] = 0.f;
  } else {
#pragma unroll
    for (int c = 0; c < 5; ++c) {
      float s = 0.f;
#pragma unroll
      for (int ch = 0; ch < NCH; ++ch)
        s += part[((size_t)ch * N_PTS + row) * 5 + c];
      df[c] = C * s;
    }
  }
  float yv[5];
#pragma unroll
  for (int c = 0; c < 5; ++c) yv[c] = y[row * 5 + c];
  float living = 1.f - yv[4];
  float inf_t = beta * yv[0] * yv[2] / living;
  float f[5];
  f[0] = -inf_t;
  f[1] = inf_t - sigma * yv[1];
  f[2] = sigma * yv[1] - (gamma + mu) * yv[2];
  f[3] = gamma * yv[2];
  f[4] = mu * yv[2];
  float s = 0.f;
#pragma unroll
  for (int c = 0; c < 5; ++c) { float d = df[c] - f[c]; s += d * d; }

  red[tid] = s;
  __syncthreads();
  for (int off = 64; off; off >>= 1) {
    if (tid < off) red[tid] += red[tid + off];
    __syncthreads();
  }
  if (tid == 0) bpart[blockIdx.x] = red[0];
}

__global__ void finish_kernel(const float* __restrict__ bpart, float* __restrict__ out) {
  if (threadIdx.x == 0) {
    float s = 0.f;
    for (int i = 0; i < 64; ++i) s += bpart[i];
    out[0] = s / (float)(N_PTS * 5);
  }
}

// ---------------- launch ----------------------------------------------------
extern "C" void kernel_launch(void* const* d_in, const int* in_sizes, int n_in,
                              void* d_out, int out_size, void* d_ws, size_t ws_size,
                              hipStream_t stream) {
  const float* t     = (const float*)d_in[0];
  const float* W_in  = (const float*)d_in[1];
  const float* b_in  = (const float*)d_in[2];
  const float* Wh    = (const float*)d_in[3];
  const float* bh    = (const float*)d_in[4];
  const float* W_out = (const float*)d_in[5];
  const float* b_out = (const float*)d_in[6];
  const float* rbta  = (const float*)d_in[7];
  const float* rsig  = (const float*)d_in[8];
  const float* rgam  = (const float*)d_in[9];
  const float* rmu   = (const float*)d_in[10];
  const float* zalp  = (const float*)d_in[11];

  char* wsb = (char*)d_ws;
  unsigned short* WT = (unsigned short*)(wsb + OFF_WT);
  float* y     = (float*)(wsb + OFF_Y);
  float* dpsi  = (float*)(wsb + OFF_DPSI);
  float* wsw   = (float*)(wsb + OFF_WSW);
  float* part  = (float*)(wsb + OFF_PART);
  float* bpart = (float*)(wsb + OFF_BPART);
  float* out   = (float*)d_out;

  // 0) W transpose + split into interleaved layout
  wprep_kernel<<<dim3(16, 16, 5), 256, 0, stream>>>(Wh, WT);

  // 1) fused MLP (input layer + 5 hidden + output/softmax)
  mlp_fused_kernel<<<N_PTS / 32, 512, 0, stream>>>(
      t, W_in, b_in, WT, bh, W_out, b_out, y);

  // 2) Caputo weights + dpsi
  prep_caputo_kernel<<<160, 256, 0, stream>>>(zalp, y, wsw, dpsi);

  // 3) Toeplitz conv partials
  conv_kernel<<<dim3(N_PTS / 256, NCH), 256, 0, stream>>>(dpsi, wsw, part);

  // 4) combine + residual + reduce
  combine_kernel<<<N_PTS / 128, 128, 0, stream>>>(y, part, rbta, rsig, rgam, rmu,
                                                  zalp, bpart);
  finish_kernel<<<1, 64, 0, stream>>>(bpart, out);
  (void)in_sizes; (void)n_in; (void)out_size; (void)ws_size;
}

// Round 11
// 132.722 us; speedup vs baseline: 1.6566x; 1.1975x over previous
//
#include <hip/hip_runtime.h>
#include <math.h>

typedef short short8v __attribute__((ext_vector_type(8)));
typedef float float4v __attribute__((ext_vector_type(4)));

#define N_PTS 8192
#define HDIM  512
#define NHID  5
#define KSTR  1024   // shorts per activation/weight row: 16 kb x (32 hi + 32 lo)
#define NCH   16     // conv j-chunks of 512

// byte offsets in workspace
#define OFF_XA    0ull
#define OFF_XB    16777216ull
#define OFF_WT    33554432ull
#define OFF_Y     38797312ull
#define OFF_PART  39157760ull
#define OFF_BPART 41779200ull

__device__ __forceinline__ unsigned short f2bf(float x) {
  unsigned u = __builtin_bit_cast(unsigned, x);
  u += 0x7FFFu + ((u >> 16) & 1u);
  return (unsigned short)(u >> 16);
}
__device__ __forceinline__ float bf2f(unsigned short h) {
  unsigned u = ((unsigned)h) << 16;
  return __builtin_bit_cast(float, u);
}

#define GLOAD16(gsrc, ldst) \
  __builtin_amdgcn_global_load_lds( \
      (const __attribute__((address_space(1))) void*)(gsrc), \
      (__attribute__((address_space(3))) void*)(ldst), 16, 0, 0)

// ---------------- merged prep: W transpose/split + layer0 -------------------
// blocks 0..1279: Wh [5][512k][512n] f32 -> WT [5][512n][16kb][32hi|32lo]
// blocks 1280..5375: layer0  h = tanh(t*Win+bin) -> X split/interleaved
__global__ void prep_kernel(const float* __restrict__ Wh,
                            unsigned short* __restrict__ WT,
                            const float* __restrict__ t,
                            const float* __restrict__ Win,
                            const float* __restrict__ bin,
                            unsigned short* __restrict__ X) {
  int bid = blockIdx.x;
  if (bid < 1280) {
    __shared__ float tile[32][33];
    int kb = bid & 15, n0 = ((bid >> 4) & 15) * 32, l = bid >> 8;
    int j = threadIdx.x & 31, i8 = threadIdx.x >> 5;
    const float* W = Wh + (size_t)l * HDIM * HDIM;
#pragma unroll
    for (int q = 0; q < 4; ++q)
      tile[i8 + 8 * q][j] = W[(size_t)(kb * 32 + i8 + 8 * q) * HDIM + n0 + j];
    __syncthreads();
#pragma unroll
    for (int q = 0; q < 4; ++q) {
      int n = n0 + i8 + 8 * q;
      float v = tile[j][i8 + 8 * q];
      unsigned short h = f2bf(v);
      unsigned short lo = f2bf(v - bf2f(h));
      size_t o = ((size_t)l * HDIM + n) * KSTR + kb * 64 + j;
      WT[o] = h; WT[o + 32] = lo;
    }
  } else {
    int gid = (bid - 1280) * 256 + threadIdx.x;
    int row = gid >> 7;
    int jq  = (gid & 127) << 2;
    float tv = t[row];
    float4 w = *(const float4*)(Win + jq);
    float4 b = *(const float4*)(bin + jq);
    float v[4];
    v[0] = tanhf(tv * w.x + b.x); v[1] = tanhf(tv * w.y + b.y);
    v[2] = tanhf(tv * w.z + b.z); v[3] = tanhf(tv * w.w + b.w);
    ushort4 h4, l4;
    h4.x = f2bf(v[0]); l4.x = f2bf(v[0] - bf2f(h4.x));
    h4.y = f2bf(v[1]); l4.y = f2bf(v[1] - bf2f(h4.y));
    h4.z = f2bf(v[2]); l4.z = f2bf(v[2] - bf2f(h4.z));
    h4.w = f2bf(v[3]); l4.w = f2bf(v[3] - bf2f(h4.w));
    size_t o = (size_t)row * KSTR + (jq >> 5) * 64 + (jq & 31);
    *(ushort4*)(X + o) = h4;
    *(ushort4*)(X + o + 32) = l4;
  }
}

// ---------------- split-bf16 MFMA GEMM + tanh + re-split --------------------
// tile 64x128, BK=32, 8 waves (512 thr) in 2x4, wave tile 32x32 (M2/N2)
// grid (128,4)=512 blocks = 2 blocks/CU = 16 waves/CU (4/SIMD).
// 3-buffer LDS (72 KB), 2-deep prefetch, counted vmcnt(3), raw s_barrier,
// setprio on MFMA. LDS row = 128B = 8 slots; slot ^= (row&7) on BOTH sides.
__global__ __launch_bounds__(512, 4) void gemm_split_kernel(
    const unsigned short* __restrict__ A,    // [8192][KSTR]
    const unsigned short* __restrict__ Bt,   // [512][KSTR]
    const float* __restrict__ bias,
    unsigned short* __restrict__ C) {        // [8192][KSTR]
  // per buffer (shorts): A 0..4095 (64 rows), B 4096..12287 (128 cols)
  __shared__ __align__(16) short lds[3][12288];   // 72 KB
  const int tid = threadIdx.x;
  const int lane = tid & 63, w = tid >> 6;
  const int wr = w >> 2, wc = w & 3;             // 2x4 wave grid
  const int r0 = blockIdx.x * 64, c0 = blockIdx.y * 128;
  const int rl = lane & 15, kgrp = lane >> 4;

  float4v acc[2][2];
#pragma unroll
  for (int i = 0; i < 2; ++i)
#pragma unroll
    for (int j = 0; j < 2; ++j) acc[i][j] = (float4v){0.f, 0.f, 0.f, 0.f};

  auto stage = [&](int b, int kt) {
    const int kbase = kt * 64;
    // A tile: 64 rows x 8 chunks = 512, 1 per thread
    {
      int c = tid;
      int row = c >> 3, m = c & 7;
      int gs = m ^ (row & 7);
      GLOAD16(A + (size_t)(r0 + row) * KSTR + kbase + gs * 8,
              &lds[b][(w * 64) * 8]);
    }
    // B tile: 128 cols x 8 chunks = 1024, 2 per thread
#pragma unroll
    for (int i = 0; i < 2; ++i) {
      int c = i * 512 + tid;
      int col = c >> 3, m = c & 7;
      int gs = m ^ (col & 7);
      GLOAD16(Bt + (size_t)(c0 + col) * KSTR + kbase + gs * 8,
              &lds[b][4096 + (i * 512 + w * 64) * 8]);
    }
  };

  stage(0, 0);
  stage(1, 1);
  asm volatile("s_waitcnt vmcnt(3)" ::: "memory");   // stage0 complete
  __builtin_amdgcn_s_barrier();
  asm volatile("" ::: "memory");

#pragma unroll 1
  for (int kt = 0; kt < 16; ++kt) {
    if (kt < 14) stage((kt + 2) % 3, kt + 2);        // 2-deep prefetch
    const short* bufc = lds[kt % 3];
    short8v ahi[2], alo[2], bhi[2], blo[2];
#pragma unroll
    for (int mi = 0; mi < 2; ++mi) {
      int row = wr * 32 + mi * 16 + rl;
      int sh = kgrp ^ (row & 7);
      int sl = (kgrp + 4) ^ (row & 7);
      ahi[mi] = *(const short8v*)&bufc[row * 64 + sh * 8];
      alo[mi] = *(const short8v*)&bufc[row * 64 + sl * 8];
    }
#pragma unroll
    for (int ni = 0; ni < 2; ++ni) {
      int col = wc * 32 + ni * 16 + rl;
      int sh = kgrp ^ (col & 7);
      int sl = (kgrp + 4) ^ (col & 7);
      bhi[ni] = *(const short8v*)&bufc[4096 + col * 64 + sh * 8];
      blo[ni] = *(const short8v*)&bufc[4096 + col * 64 + sl * 8];
    }
    __builtin_amdgcn_s_setprio(1);
#pragma unroll
    for (int mi = 0; mi < 2; ++mi)
#pragma unroll
      for (int ni = 0; ni < 2; ++ni)
        acc[mi][ni] = __builtin_amdgcn_mfma_f32_16x16x32_bf16(ahi[mi], bhi[ni], acc[mi][ni], 0, 0, 0);
#pragma unroll
    for (int mi = 0; mi < 2; ++mi)
#pragma unroll
      for (int ni = 0; ni < 2; ++ni)
        acc[mi][ni] = __builtin_amdgcn_mfma_f32_16x16x32_bf16(ahi[mi], blo[ni], acc[mi][ni], 0, 0, 0);
#pragma unroll
    for (int mi = 0; mi < 2; ++mi)
#pragma unroll
      for (int ni = 0; ni < 2; ++ni)
        acc[mi][ni] = __builtin_amdgcn_mfma_f32_16x16x32_bf16(alo[mi], bhi[ni], acc[mi][ni], 0, 0, 0);
    __builtin_amdgcn_s_setprio(0);
    if (kt < 15) {
      if (kt < 14) asm volatile("s_waitcnt vmcnt(3)" ::: "memory"); // kt+1 ready
      else         asm volatile("s_waitcnt vmcnt(0)" ::: "memory"); // drain
      __builtin_amdgcn_s_barrier();
      asm volatile("" ::: "memory");
    }
  }

  float bcol[2];
#pragma unroll
  for (int ni = 0; ni < 2; ++ni) bcol[ni] = bias[c0 + wc * 32 + ni * 16 + rl];
#pragma unroll
  for (int mi = 0; mi < 2; ++mi)
#pragma unroll
    for (int ni = 0; ni < 2; ++ni)
#pragma unroll
      for (int r = 0; r < 4; ++r) {
        int row = r0 + wr * 32 + mi * 16 + kgrp * 4 + r;
        int col = c0 + wc * 32 + ni * 16 + rl;
        float v = tanhf(acc[mi][ni][r] + bcol[ni]);
        unsigned short h = f2bf(v);
        unsigned short lo = f2bf(v - bf2f(h));
        size_t o = (size_t)row * KSTR + (col >> 5) * 64 + (col & 31);
        C[o] = h; C[o + 32] = lo;
      }
}

// ---------------- output layer: y = softmax(h @ W_out + b_out) --------------
__global__ void outlayer_kernel(const unsigned short* __restrict__ X,
                                const float* __restrict__ Wout,
                                const float* __restrict__ bout,
                                float* __restrict__ y) {
  int wid  = threadIdx.x >> 6;
  int lane = threadIdx.x & 63;
  int row  = blockIdx.x * 4 + wid;
  size_t o = (size_t)row * KSTR + (lane >> 2) * 64 + (lane & 3) * 8;
  short8v hv = *(const short8v*)(X + o);
  short8v lv = *(const short8v*)(X + o + 32);
  const float* wrp = Wout + lane * 40;
  float acc[5] = {0.f, 0.f, 0.f, 0.f, 0.f};
#pragma unroll
  for (int e = 0; e < 8; ++e) {
    float h = bf2f((unsigned short)hv[e]) + bf2f((unsigned short)lv[e]);
#pragma unroll
    for (int c = 0; c < 5; ++c) acc[c] += h * wrp[e * 5 + c];
  }
#pragma unroll
  for (int c = 0; c < 5; ++c)
    for (int off = 32; off; off >>= 1) acc[c] += __shfl_down(acc[c], off);
  if (lane == 0) {
    float l[5], m = -1e30f;
#pragma unroll
    for (int c = 0; c < 5; ++c) { l[c] = acc[c] + bout[c]; m = fmaxf(m, l[c]); }
    float s = 0.f;
#pragma unroll
    for (int c = 0; c < 5; ++c) { l[c] = expf(l[c] - m); s += l[c]; }
    float inv = 1.f / s;
#pragma unroll
    for (int c = 0; c < 5; ++c) y[row * 5 + c] = l[c] * inv;
  }
}

// ---------------- Toeplitz conv partials (chunks of 512) --------------------
// dpsi computed in-LDS from y; ws weights computed inline (double precision).
__global__ __launch_bounds__(256) void conv_kernel(
    const float* __restrict__ y, const float* __restrict__ za,
    float* __restrict__ part) {
  __shared__ float dps[256][8];
  __shared__ float wsl[512];
  int tid = threadIdx.x;
  int r0  = blockIdx.x * 256;
  int ch  = blockIdx.y;
  int r   = r0 + tid;
  float acc[5] = {0.f, 0.f, 0.f, 0.f, 0.f};

  double z = (double)za[0];
  double alpha = 0.6 + 0.4 / (1.0 + exp(-z));
  double p = 1.0 - alpha;

  for (int t4 = 0; t4 < 2; ++t4) {
    int j0 = ch * 512 + t4 * 256;
    if (j0 > r0 + 254) break;             // block-uniform
    __syncthreads();
    {
      int jr = j0 + tid;
      if (jr <= N_PTS - 2) {
        const float* y0 = y + (size_t)jr * 5;
        dps[tid][0] = y0[5] - y0[0]; dps[tid][1] = y0[6] - y0[1];
        dps[tid][2] = y0[7] - y0[2]; dps[tid][3] = y0[8] - y0[3];
        dps[tid][4] = y0[9] - y0[4];
      } else {
        dps[tid][0] = dps[tid][1] = dps[tid][2] = dps[tid][3] = dps[tid][4] = 0.f;
      }
    }
    int base = r0 - j0 - 256;
#pragma unroll
    for (int s = 0; s < 2; ++s) {
      int i = tid + s * 256;
      int src = base + i;
      float wv = 0.f;
      if (src >= 0 && src < N_PTS - 1) {
        double ww = pow((double)src + 1.0, p) -
                    (src == 0 ? 0.0 : pow((double)src, p));
        wv = (float)ww;
      }
      wsl[i] = wv;
    }
    __syncthreads();
    int widx = tid + 255;
#pragma unroll 4
    for (int jj = 0; jj < 256; ++jj) {
      float w = wsl[widx - jj];           // zero-padded outside valid lags
      float4 d4 = *(const float4*)&dps[jj][0];
      float d5 = dps[jj][4];
      acc[0] += w * d4.x; acc[1] += w * d4.y; acc[2] += w * d4.z;
      acc[3] += w * d4.w; acc[4] += w * d5;
    }
  }
  float* pp = part + ((size_t)ch * N_PTS + r) * 5;
  pp[0] = acc[0]; pp[1] = acc[1]; pp[2] = acc[2]; pp[3] = acc[3]; pp[4] = acc[4];
}

// ---------------- combine partials + residual + block reduce ----------------
__device__ __forceinline__ float softplusf_(float x) {
  return x > 20.f ? x : log1pf(expf(x));
}

__global__ void combine_kernel(const float* __restrict__ y,
                               const float* __restrict__ part,
                               const float* __restrict__ rb, const float* __restrict__ rs,
                               const float* __restrict__ rg, const float* __restrict__ rm,
                               const float* __restrict__ za,
                               float* __restrict__ bpart) {
  __shared__ float red[128];
  int tid = threadIdx.x;
  int row = blockIdx.x * 128 + tid;

  float beta  = softplusf_(rb[0]);
  float sigma = softplusf_(rs[0]);
  float gamma = softplusf_(rg[0]);
  float mu    = softplusf_(rm[0]);
  double z = (double)za[0];
  double alpha = 0.6 + 0.4 / (1.0 + exp(-z));
  float C = (float)(pow(0.1, -alpha) / tgamma(2.0 - alpha));

  float df[5];
  if (row == 0) {
    df[0] = df[1] = df[2] = df[3] = df[4] = 0.f;
  } else {
#pragma unroll
    for (int c = 0; c < 5; ++c) {
      float s = 0.f;
#pragma unroll
      for (int ch = 0; ch < NCH; ++ch)
        s += part[((size_t)ch * N_PTS + row) * 5 + c];
      df[c] = C * s;
    }
  }
  float yv[5];
#pragma unroll
  for (int c = 0; c < 5; ++c) yv[c] = y[row * 5 + c];
  float living = 1.f - yv[4];
  float inf_t = beta * yv[0] * yv[2] / living;
  float f[5];
  f[0] = -inf_t;
  f[1] = inf_t - sigma * yv[1];
  f[2] = sigma * yv[1] - (gamma + mu) * yv[2];
  f[3] = gamma * yv[2];
  f[4] = mu * yv[2];
  float s = 0.f;
#pragma unroll
  for (int c = 0; c < 5; ++c) { float d = df[c] - f[c]; s += d * d; }

  red[tid] = s;
  __syncthreads();
  for (int off = 64; off; off >>= 1) {
    if (tid < off) red[tid] += red[tid + off];
    __syncthreads();
  }
  if (tid == 0) bpart[blockIdx.x] = red[0];
}

__global__ void finish_kernel(const float* __restrict__ bpart, float* __restrict__ out) {
  if (threadIdx.x == 0) {
    float s = 0.f;
    for (int i = 0; i < 64; ++i) s += bpart[i];
    out[0] = s / (float)(N_PTS * 5);
  }
}

// ---------------- launch ----------------------------------------------------
extern "C" void kernel_launch(void* const* d_in, const int* in_sizes, int n_in,
                              void* d_out, int out_size, void* d_ws, size_t ws_size,
                              hipStream_t stream) {
  const float* t     = (const float*)d_in[0];
  const float* W_in  = (const float*)d_in[1];
  const float* b_in  = (const float*)d_in[2];
  const float* Wh    = (const float*)d_in[3];
  const float* bh    = (const float*)d_in[4];
  const float* W_out = (const float*)d_in[5];
  const float* b_out = (const float*)d_in[6];
  const float* rbta  = (const float*)d_in[7];
  const float* rsig  = (const float*)d_in[8];
  const float* rgam  = (const float*)d_in[9];
  const float* rmu   = (const float*)d_in[10];
  const float* zalp  = (const float*)d_in[11];

  char* wsb = (char*)d_ws;
  unsigned short* XA = (unsigned short*)(wsb + OFF_XA);
  unsigned short* XB = (unsigned short*)(wsb + OFF_XB);
  unsigned short* WT = (unsigned short*)(wsb + OFF_WT);
  float* y     = (float*)(wsb + OFF_Y);
  float* part  = (float*)(wsb + OFF_PART);
  float* bpart = (float*)(wsb + OFF_BPART);
  float* out   = (float*)d_out;

  // 0) merged prep: W transpose/split + layer0
  prep_kernel<<<5376, 256, 0, stream>>>(Wh, WT, t, W_in, b_in, XA);

  // 1) 5 hidden layers, ping-pong
  for (int l = 0; l < NHID; ++l) {
    const unsigned short* in = (l & 1) ? XB : XA;
    unsigned short*      oub = (l & 1) ? XA : XB;
    gemm_split_kernel<<<dim3(N_PTS / 64, HDIM / 128), 512, 0, stream>>>(
        in, WT + (size_t)l * HDIM * KSTR, bh + (size_t)l * HDIM, oub);
  }
  // NHID=5 -> final activations in XB

  // 2) output layer + softmax
  outlayer_kernel<<<N_PTS / 4, 256, 0, stream>>>(XB, W_out, b_out, y);

  // 3) Toeplitz conv partials (dpsi + ws weights computed inline)
  conv_kernel<<<dim3(N_PTS / 256, NCH), 256, 0, stream>>>(y, zalp, part);

  // 4) combine + residual + reduce
  combine_kernel<<<N_PTS / 128, 128, 0, stream>>>(y, part, rbta, rsig, rgam, rmu,
                                                  zalp, bpart);
  finish_kernel<<<1, 64, 0, stream>>>(bpart, out);
  (void)in_sizes; (void)n_in; (void)out_size; (void)ws_size;
}